// Round 14
// baseline (137.702 us; speedup 1.0000x reference)
//
#include <hip/hip_runtime.h>
#include <stdint.h>

#define B_ 4
#define C_ 256
#define P_ 4096
#define H_ 4
#define EPS_ 1e-5f
#define LOG2E 1.4426950408889634f

typedef __attribute__((ext_vector_type(8))) short short8v;
typedef __attribute__((ext_vector_type(4))) float floatx4;
#define MFMA16 __builtin_amdgcn_mfma_f32_16x16x32_bf16

#define GLOAD16(gp, lp)                                                     \
  __builtin_amdgcn_global_load_lds(                                         \
      (const __attribute__((address_space(1))) uint32_t*)(gp),              \
      (__attribute__((address_space(3))) uint32_t*)(lp), 16, 0, 0)

#define EXP2IP(x) asm("v_exp_f32 %0, %0" : "+v"(x))

__device__ __forceinline__ ushort f2bf(float f) {
  union { float f; uint32_t u; } c; c.f = f;
  uint32_t r = c.u + 0x7FFFu + ((c.u >> 16) & 1u);
  return (ushort)(r >> 16);
}
__device__ __forceinline__ float bf2f(ushort u) {
  union { uint32_t u; float f; } c; c.u = ((uint32_t)u) << 16; return c.f;
}

// ---------------------------------------------------------------------------
// Kernel 0: cast+transpose  x[b][c][p] f32  ->  xb[b][p][c] bf16
// ---------------------------------------------------------------------------
__global__ __launch_bounds__(256) void cast_kernel(
    const float* __restrict__ x, ushort* __restrict__ xb) {
  const int p0 = blockIdx.x * 64;
  const int c0 = blockIdx.y * 64;
  const int b = blockIdx.z;
  __shared__ float Ls[64][69];
  const int t = threadIdx.x;
#pragma unroll
  for (int r = 0; r < 4; r++) {
    int g = t + r * 256;
    int c = g >> 4, p4 = (g & 15) * 4;
    *(float4*)&Ls[c][p4] =
        *(const float4*)&x[((size_t)(b * C_ + c0 + c)) * P_ + p0 + p4];
  }
  __syncthreads();
  const int p = t >> 2, cs = (t & 3) * 16;
  size_t rowb = ((size_t)b * P_ + p0 + p) * 256 + c0 + cs;
#pragma unroll
  for (int u = 0; u < 4; u++) {
    ushort4 o;
    o.x = f2bf(Ls[cs + u * 4 + 0][p]);
    o.y = f2bf(Ls[cs + u * 4 + 1][p]);
    o.z = f2bf(Ls[cs + u * 4 + 2][p]);
    o.w = f2bf(Ls[cs + u * 4 + 3][p]);
    *(ushort4*)&xb[rowb + u * 4] = o;
  }
}

// ---------------------------------------------------------------------------
// Kernel 1: QKV projections, bf16 MFMA.
//   q/k out: [b][h][p][d] bf16 (q pre-scaled by 0.125*log2e).
//   v  out: [b][c][p] with per-64-key-tile slot permutation baked in
//   (attn's PV consumes the QK^T C-layout directly, zero P routing).
// ---------------------------------------------------------------------------
__global__ __launch_bounds__(256) void proj_kernel(
    const ushort* __restrict__ xb, const float* __restrict__ wq,
    const float* __restrict__ wk, const float* __restrict__ wv,
    ushort* __restrict__ q, ushort* __restrict__ k, ushort* __restrict__ v) {
  const int p0 = blockIdx.x * 256;
  const int which = blockIdx.y >> 2;
  const int o0 = (blockIdx.y & 3) * 64;
  const int b = blockIdx.z;
  const float* __restrict__ w = (which == 0) ? wq : (which == 1) ? wk : wv;
  const float scale = (which == 0) ? 0.125f * LOG2E : 1.0f;

  __shared__ __align__(16) uint8_t smem[33280];
  ushort* As = (ushort*)smem;  // [64 m][256 k], 8-chunk XOR swizzle
  const int t = threadIdx.x;
  const int lane = t & 63, wid = t >> 6, lr = lane & 15, lg = lane >> 4;

#pragma unroll
  for (int r = 0; r < 8; r++) {
    int g = t + r * 256;
    int m = g >> 5, ch = g & 31;
    const float* wr = &w[(size_t)(o0 + m) * 256 + ch * 8];
    float4 wa = *(const float4*)wr, wb = *(const float4*)(wr + 4);
    short8v s;
    s[0] = f2bf(wa.x * scale); s[1] = f2bf(wa.y * scale);
    s[2] = f2bf(wa.z * scale); s[3] = f2bf(wa.w * scale);
    s[4] = f2bf(wb.x * scale); s[5] = f2bf(wb.y * scale);
    s[6] = f2bf(wb.z * scale); s[7] = f2bf(wb.w * scale);
    *(short8v*)&As[m * 256 + (ch ^ (m & 7)) * 8] = s;
  }
  __syncthreads();

  const int pw0 = p0 + wid * 64;
  floatx4 acc[4][4];
#pragma unroll
  for (int mt = 0; mt < 4; mt++)
#pragma unroll
    for (int pt = 0; pt < 4; pt++) acc[mt][pt] = (floatx4){0.f, 0.f, 0.f, 0.f};

#pragma unroll
  for (int ks = 0; ks < 4; ks++) {
    const int k0 = ks * 64;
    const int cb = k0 >> 3;
    short8v bf[4][2];
#pragma unroll
    for (int pt = 0; pt < 4; pt++)
#pragma unroll
      for (int kh = 0; kh < 2; kh++)
        bf[pt][kh] = *(const short8v*)&xb[((size_t)b * P_ + pw0 + pt * 16 + lr) * 256 +
                                          k0 + kh * 32 + lg * 8];
#pragma unroll
    for (int mt = 0; mt < 4; mt++) {
      int m = mt * 16 + lr;
      short8v a0 = *(const short8v*)&As[m * 256 + ((cb + lg) ^ (m & 7)) * 8];
      short8v a1 = *(const short8v*)&As[m * 256 + ((cb + 4 + lg) ^ (m & 7)) * 8];
#pragma unroll
      for (int pt = 0; pt < 4; pt++) {
        acc[mt][pt] = MFMA16(a0, bf[pt][0], acc[mt][pt], 0, 0, 0);
        acc[mt][pt] = MFMA16(a1, bf[pt][1], acc[mt][pt], 0, 0, 0);
      }
    }
  }

  if (which < 2) {
    ushort* out = (which == 0) ? q : k;
    const int h = o0 >> 6;
#pragma unroll
    for (int pt = 0; pt < 4; pt++) {
      size_t prow = ((size_t)(b * H_ + h) * P_ + pw0 + pt * 16 + lr) * 64;
#pragma unroll
      for (int mt = 0; mt < 4; mt++) {
        ushort4 s;
        s.x = f2bf(acc[mt][pt][0]); s.y = f2bf(acc[mt][pt][1]);
        s.z = f2bf(acc[mt][pt][2]); s.w = f2bf(acc[mt][pt][3]);
        *(ushort4*)&out[prow + mt * 16 + 4 * lg] = s;
      }
    }
  } else {
    __syncthreads();
    ushort* Vt = (ushort*)smem;  // [64 c][260 p]  (slot-permuted per wid-block)
#pragma unroll
    for (int mt = 0; mt < 4; mt++)
#pragma unroll
      for (int rr = 0; rr < 4; rr++) {
        int c = mt * 16 + 4 * lg + rr;
#pragma unroll
        for (int pt = 0; pt < 4; pt++) {
          int s = 32 * (pt >> 1) + 8 * (lr >> 2) + 4 * (pt & 1) + (lr & 3);
          Vt[c * 260 + wid * 64 + s] = f2bf(acc[mt][pt][rr]);
        }
      }
    __syncthreads();
#pragma unroll
    for (int r = 0; r < 8; r++) {
      int g = t + r * 256;
      int cr = g >> 5, seg = g & 31;
      *(short8v*)&v[((size_t)(b * C_ + o0 + cr)) * P_ + p0 + seg * 8] =
          *(const short8v*)&Vt[cr * 260 + seg * 8];
    }
  }
}

// ---------------------------------------------------------------------------
// Kernel 2: flash attention.  512 threads = 8 waves. QBLK=128.
// qgrp=w&3 owns 32 queries; jgrp=w>>2 does even/odd 64-key tiles.
// Raw-exp2 softmax (no max shift; scale cancels in O/l); P packed straight
// into PV B-operand (V slot-permuted at proj); l via ones-MFMA;
// compile-time LDS addressing; gload_lds dbuf, counted vmcnt. No setprio.
// (r11-exact: verified 71.1 us / absmax 0.109.)
// grid (P/128, H, B).
// ---------------------------------------------------------------------------
__global__ __launch_bounds__(512, 4) void attn_kernel(
    const ushort* __restrict__ q, const ushort* __restrict__ k,
    const ushort* __restrict__ v, const ushort* __restrict__ xb,
    ushort* __restrict__ dmT) {
  const int i0 = blockIdx.x * 128;
  const int h = blockIdx.y;
  const int b = blockIdx.z;
  const int t = threadIdx.x;
  const int lane = t & 63, w = t >> 6, lr = lane & 15, lg = lane >> 4;
  const int qgrp = w & 3, jgrp = w >> 2;

  // jgrp block: buf0 @jgrp*32768, buf1 @+16384; each buf: K 8KB | V 8KB
  __shared__ __align__(16) uint8_t smem[65536];

  const size_t bh = (size_t)(b * H_ + h);
  const ushort* __restrict__ qg = q + bh * P_ * 64;
  const ushort* __restrict__ kb = k + bh * P_ * 64;
  const ushort* __restrict__ vb = v + ((size_t)(b * C_ + h * 64)) * P_;

  // Q fragments (B operand: col i, k = d)
  short8v bq0[2], bq1[2];
#pragma unroll
  for (int qb2 = 0; qb2 < 2; qb2++) {
    const ushort* qrow = qg + ((size_t)(i0 + qgrp * 32 + qb2 * 16 + lr)) * 64;
    bq0[qb2] = *(const short8v*)&qrow[lg * 8];
    bq1[qb2] = *(const short8v*)&qrow[32 + lg * 8];
  }

  // all-ones A fragment (bf16 1.0) for the l-row MFMA
  short8v a_ones;
#pragma unroll
  for (int e = 0; e < 8; e++) a_ones[e] = (short)0x3F80;

  // hoisted per-lane LDS read bases (element offsets; all else is constant)
  const int sw = lr & 7;
  const ushort* rb0 = (const ushort*)smem + jgrp * 16384 + lr * 64 + ((lg ^ sw) << 3);
  const ushort* rb1 = (const ushort*)smem + jgrp * 16384 + lr * 64 + (((4 + lg) ^ sw) << 3);

  // staging: running global pointers (advance by const per step)
  const int rws = lane >> 3;
  const int srow = qgrp * 16 + rws;
  const int csw = ((lane & 7) ^ rws) * 8;
  const ushort* kg = kb + (size_t)srow * 64 + csw + (size_t)jgrp * 4096;
  const ushort* vg = vb + (size_t)srow * P_ + csw + jgrp * 64;
  ushort* kd0 = (ushort*)(smem + jgrp * 32768) + qgrp * 1024;   // buf sel=0 K dest

  floatx4 o_acc[2][4], lacc[2];
#pragma unroll
  for (int qb2 = 0; qb2 < 2; qb2++) {
    lacc[qb2] = (floatx4){0.f, 0.f, 0.f, 0.f};
#pragma unroll
    for (int dt = 0; dt < 4; dt++) o_acc[qb2][dt] = (floatx4){0.f, 0.f, 0.f, 0.f};
  }

#define STAGE_(SEL)                                                         \
  do {                                                                      \
    ushort* _kd = kd0 + (SEL) * 8192;                                       \
    GLOAD16(kg, _kd);                                                       \
    GLOAD16(kg + 512, _kd + 512);                                           \
    GLOAD16(vg, _kd + 4096);                                                \
    GLOAD16(vg + 8 * (size_t)P_, _kd + 4608);                               \
    kg += 8192;                                                             \
    vg += 128;                                                              \
  } while (0)

#define COMPUTE_(SEL)                                                       \
  do {                                                                      \
    floatx4 st[2][4];                                                       \
    _Pragma("unroll") for (int jt = 0; jt < 4; jt++) {                      \
      short8v a0 = *(const short8v*)&rb0[(SEL) * 8192 + jt * 1024];         \
      short8v a1 = *(const short8v*)&rb1[(SEL) * 8192 + jt * 1024];         \
      floatx4 c0 = (floatx4){0.f, 0.f, 0.f, 0.f};                           \
      c0 = MFMA16(a0, bq0[0], c0, 0, 0, 0);                                 \
      c0 = MFMA16(a1, bq1[0], c0, 0, 0, 0);                                 \
      st[0][jt] = c0;                                                       \
      floatx4 c1 = (floatx4){0.f, 0.f, 0.f, 0.f};                           \
      c1 = MFMA16(a0, bq0[1], c1, 0, 0, 0);                                 \
      c1 = MFMA16(a1, bq1[1], c1, 0, 0, 0);                                 \
      st[1][jt] = c1;                                                       \
    }                                                                       \
    short8v bp0[2], bp1[2];                                                 \
    _Pragma("unroll") for (int qb2 = 0; qb2 < 2; qb2++) {                   \
      _Pragma("unroll") for (int jt = 0; jt < 4; jt++) {                    \
        EXP2IP(st[qb2][jt][0]); EXP2IP(st[qb2][jt][1]);                     \
        EXP2IP(st[qb2][jt][2]); EXP2IP(st[qb2][jt][3]);                     \
      }                                                                     \
      union { short8v v8; uint32_t d[4]; } u0, u1;                          \
      asm("v_cvt_pk_bf16_f32 %0, %1, %2" : "=v"(u0.d[0]) : "v"(st[qb2][0][0]), "v"(st[qb2][0][1])); \
      asm("v_cvt_pk_bf16_f32 %0, %1, %2" : "=v"(u0.d[1]) : "v"(st[qb2][0][2]), "v"(st[qb2][0][3])); \
      asm("v_cvt_pk_bf16_f32 %0, %1, %2" : "=v"(u0.d[2]) : "v"(st[qb2][1][0]), "v"(st[qb2][1][1])); \
      asm("v_cvt_pk_bf16_f32 %0, %1, %2" : "=v"(u0.d[3]) : "v"(st[qb2][1][2]), "v"(st[qb2][1][3])); \
      asm("v_cvt_pk_bf16_f32 %0, %1, %2" : "=v"(u1.d[0]) : "v"(st[qb2][2][0]), "v"(st[qb2][2][1])); \
      asm("v_cvt_pk_bf16_f32 %0, %1, %2" : "=v"(u1.d[1]) : "v"(st[qb2][2][2]), "v"(st[qb2][2][3])); \
      asm("v_cvt_pk_bf16_f32 %0, %1, %2" : "=v"(u1.d[2]) : "v"(st[qb2][3][0]), "v"(st[qb2][3][1])); \
      asm("v_cvt_pk_bf16_f32 %0, %1, %2" : "=v"(u1.d[3]) : "v"(st[qb2][3][2]), "v"(st[qb2][3][3])); \
      bp0[qb2] = u0.v8;                                                     \
      bp1[qb2] = u1.v8;                                                     \
    }                                                                       \
    _Pragma("unroll") for (int dt = 0; dt < 4; dt++) {                      \
      short8v a0 = *(const short8v*)&rb0[(SEL) * 8192 + 4096 + dt * 1024];  \
      short8v a1 = *(const short8v*)&rb1[(SEL) * 8192 + 4096 + dt * 1024];  \
      o_acc[0][dt] = MFMA16(a0, bp0[0], o_acc[0][dt], 0, 0, 0);             \
      o_acc[0][dt] = MFMA16(a1, bp1[0], o_acc[0][dt], 0, 0, 0);             \
      o_acc[1][dt] = MFMA16(a0, bp0[1], o_acc[1][dt], 0, 0, 0);             \
      o_acc[1][dt] = MFMA16(a1, bp1[1], o_acc[1][dt], 0, 0, 0);             \
    }                                                                       \
    lacc[0] = MFMA16(a_ones, bp0[0], lacc[0], 0, 0, 0);                     \
    lacc[0] = MFMA16(a_ones, bp1[0], lacc[0], 0, 0, 0);                     \
    lacc[1] = MFMA16(a_ones, bp0[1], lacc[1], 0, 0, 0);                     \
    lacc[1] = MFMA16(a_ones, bp1[1], lacc[1], 0, 0, 0);                     \
  } while (0)

  // ---- pipeline: 32 tiles/group (even/odd interleave via jgrp) ----
  STAGE_(0);
  for (int it = 0; it < 15; ++it) {
    STAGE_(1);
    asm volatile("s_waitcnt vmcnt(8)" ::: "memory");
    __builtin_amdgcn_s_barrier();
    COMPUTE_(0);
    asm volatile("" ::: "memory");
    __builtin_amdgcn_s_barrier();
    STAGE_(0);
    asm volatile("s_waitcnt vmcnt(8)" ::: "memory");
    __builtin_amdgcn_s_barrier();
    COMPUTE_(1);
    asm volatile("" ::: "memory");
    __builtin_amdgcn_s_barrier();
  }
  STAGE_(1);
  asm volatile("s_waitcnt vmcnt(8)" ::: "memory");
  __builtin_amdgcn_s_barrier();
  COMPUTE_(0);
  asm volatile("s_waitcnt vmcnt(0)" ::: "memory");
  __builtin_amdgcn_s_barrier();
  COMPUTE_(1);
  __syncthreads();
#undef STAGE_
#undef COMPUTE_

  // ---- epilogue: combine groups, normalize, write dmT = bf16(o - x) ----
  float* Opart = (float*)smem;                  // [4 qgrp][2 qb][4 dt][256]
  float* lpart = (float*)(smem + 32768);        // [128]
  if (jgrp == 1) {
#pragma unroll
    for (int qb2 = 0; qb2 < 2; qb2++) {
#pragma unroll
      for (int dt = 0; dt < 4; dt++)
        *(floatx4*)&Opart[(((qgrp * 2 + qb2) * 4 + dt) << 8) + (lane << 2)] =
            o_acc[qb2][dt];
      if (lg == 0) lpart[qgrp * 32 + qb2 * 16 + lr] = lacc[qb2][0];
    }
  }
  __syncthreads();
  ushort* Os = (ushort*)(smem + 36864);         // [128 i][72 d]
  if (jgrp == 0) {
#pragma unroll
    for (int qb2 = 0; qb2 < 2; qb2++) {
      const int i = qgrp * 32 + qb2 * 16 + lr;
      const float invl = 1.f / (lacc[qb2][0] + lpart[i]);
#pragma unroll
      for (int dt = 0; dt < 4; dt++) {
        floatx4 o2 = o_acc[qb2][dt] +
                     *(const floatx4*)&Opart[(((qgrp * 2 + qb2) * 4 + dt) << 8) + (lane << 2)];
        uint2 pk2;
        asm("v_cvt_pk_bf16_f32 %0, %1, %2" : "=v"(pk2.x)
            : "v"(o2[0] * invl), "v"(o2[1] * invl));
        asm("v_cvt_pk_bf16_f32 %0, %1, %2" : "=v"(pk2.y)
            : "v"(o2[2] * invl), "v"(o2[3] * invl));
        *(uint2*)&Os[i * 72 + dt * 16 + 4 * lg] = pk2;
      }
    }
  }
  __syncthreads();
  const int ei = t >> 2, edq = t & 3;
  size_t rowb = ((size_t)b * P_ + i0 + ei) * 256 + h * 64 + edq * 16;
#pragma unroll
  for (int u = 0; u < 2; u++) {
    short8v xv8 = *(const short8v*)&xb[rowb + u * 8];
    short8v ov8 = *(const short8v*)&Os[ei * 72 + edq * 16 + u * 8];
    short8v res;
#pragma unroll
    for (int e = 0; e < 8; e++) {
      float d = bf2f(((const ushort*)&ov8)[e]) - bf2f(((const ushort*)&xv8)[e]);
      ((ushort*)&res)[e] = f2bf(d);
    }
    *(short8v*)&dmT[rowb + u * 8] = res;
  }
}

// ---------------------------------------------------------------------------
// Kernel 3: y = wt @ dm + bt, bf16 MFMA.  y bf16 [b][c][p].
// FUSED: per-channel BN partial sums (sum y, sum y^2) via 16-lane shfl
// reduce + one atomicAdd pair per channel-row per block.
// ---------------------------------------------------------------------------
__global__ __launch_bounds__(256) void tconv_kernel(
    const ushort* __restrict__ dmT, const float* __restrict__ wt,
    const float* __restrict__ bt, ushort* __restrict__ y,
    float* __restrict__ gs1, float* __restrict__ gs2) {
  const int p0 = blockIdx.x * 128;
  const int o0 = blockIdx.y * 64;
  const int b = blockIdx.z;
  __shared__ __align__(16) uint8_t smem[32768];
  ushort* As = (ushort*)smem;  // [64 m][256 k] swizzled
  const int t = threadIdx.x;
  const int lane = t & 63, wid = t >> 6, lr = lane & 15, lg = lane >> 4;

#pragma unroll
  for (int r = 0; r < 8; r++) {
    int g = t + r * 256;
    int m = g >> 5, ch = g & 31;
    const float* wr = &wt[(size_t)(o0 + m) * 256 + ch * 8];
    float4 wa = *(const float4*)wr, wb = *(const float4*)(wr + 4);
    short8v s;
    s[0] = f2bf(wa.x); s[1] = f2bf(wa.y); s[2] = f2bf(wa.z); s[3] = f2bf(wa.w);
    s[4] = f2bf(wb.x); s[5] = f2bf(wb.y); s[6] = f2bf(wb.z); s[7] = f2bf(wb.w);
    *(short8v*)&As[m * 256 + (ch ^ (m & 7)) * 8] = s;
  }
  __syncthreads();

  const int pw0 = p0 + wid * 32;
  floatx4 acc[4][2];
#pragma unroll
  for (int mt = 0; mt < 4; mt++)
#pragma unroll
    for (int pt = 0; pt < 2; pt++) acc[mt][pt] = (floatx4){0.f, 0.f, 0.f, 0.f};

#pragma unroll
  for (int ks = 0; ks < 4; ks++) {
    const int k0 = ks * 64;
    const int cb = k0 >> 3;
    short8v bf[2][2];
#pragma unroll
    for (int pt = 0; pt < 2; pt++)
#pragma unroll
      for (int kh = 0; kh < 2; kh++)
        bf[pt][kh] = *(const short8v*)&dmT[((size_t)b * P_ + pw0 + pt * 16 + lr) * 256 +
                                           k0 + kh * 32 + lg * 8];
#pragma unroll
    for (int mt = 0; mt < 4; mt++) {
      int m = mt * 16 + lr;
      short8v a0 = *(const short8v*)&As[m * 256 + ((cb + lg) ^ (m & 7)) * 8];
      short8v a1 = *(const short8v*)&As[m * 256 + ((cb + 4 + lg) ^ (m & 7)) * 8];
#pragma unroll
      for (int pt = 0; pt < 2; pt++) {
        acc[mt][pt] = MFMA16(a0, bf[pt][0], acc[mt][pt], 0, 0, 0);
        acc[mt][pt] = MFMA16(a1, bf[pt][1], acc[mt][pt], 0, 0, 0);
      }
    }
  }

  __syncthreads();
  ushort* Yt = (ushort*)smem;  // [64 c][132 p]
#pragma unroll
  for (int mt = 0; mt < 4; mt++) {
    float4 bv = *(const float4*)&bt[o0 + mt * 16 + 4 * lg];
#pragma unroll
    for (int rr = 0; rr < 4; rr++) {
      float bias = (rr == 0) ? bv.x : (rr == 1) ? bv.y : (rr == 2) ? bv.z : bv.w;
      int c = mt * 16 + 4 * lg + rr;
#pragma unroll
      for (int pt = 0; pt < 2; pt++)
        Yt[c * 132 + wid * 32 + pt * 16 + lr] = f2bf(acc[mt][pt][rr] + bias);
    }
  }
  __syncthreads();
#pragma unroll
  for (int r = 0; r < 4; r++) {
    int g = t + r * 256;
    int cr = g >> 4, seg = g & 15;
    short8v yv8 = *(const short8v*)&Yt[cr * 132 + seg * 8];
    *(short8v*)&y[((size_t)(b * C_ + o0 + cr)) * P_ + p0 + seg * 8] = yv8;
    // fused BN partial sums for channel o0+cr over this block's 128 p values
    float s1 = 0.f, s2 = 0.f;
#pragma unroll
    for (int e = 0; e < 8; e++) {
      float f = bf2f(((const ushort*)&yv8)[e]);
      s1 += f; s2 += f * f;
    }
#pragma unroll
    for (int off = 1; off <= 8; off <<= 1) {
      s1 += __shfl_xor(s1, off);
      s2 += __shfl_xor(s2, off);
    }
    if ((t & 15) == 0) {
      atomicAdd(&gs1[o0 + cr], s1);
      atomicAdd(&gs2[o0 + cr], s2);
    }
  }
}

// ---------------------------------------------------------------------------
// Kernel 4: BN finalize: sc/sh from accumulated per-channel sums. 1 block.
// ---------------------------------------------------------------------------
__global__ __launch_bounds__(256) void bnfinal_kernel(
    const float* __restrict__ gs1, const float* __restrict__ gs2,
    const float* __restrict__ gamma, const float* __restrict__ beta,
    float* __restrict__ sc, float* __restrict__ sh) {
  const int c = threadIdx.x;
  const float n = (float)(B_ * P_);
  float mean = gs1[c] / n;
  float var = gs2[c] / n - mean * mean;
  float rstd = rsqrtf(var + EPS_);
  float g = gamma[c] * rstd;
  sc[c] = g;
  sh[c] = beta[c] - mean * g;
}

// ---------------------------------------------------------------------------
// Kernel 5: out = x + relu(y*scale + shift); y bf16, out f32.
// ---------------------------------------------------------------------------
__global__ __launch_bounds__(256) void final_kernel(
    const float* __restrict__ x, const ushort* __restrict__ y,
    const float* __restrict__ sc, const float* __restrict__ sh,
    float* __restrict__ out) {
  const int f = blockIdx.x * 256 + threadIdx.x;
  const size_t base = (size_t)f * 8;
  const int c = (int)((base >> 12) & (C_ - 1));
  short8v yv = *(const short8v*)&y[base];
  float4 x0 = *(const float4*)&x[base];
  float4 x1 = *(const float4*)&x[base + 4];
  const float s = sc[c], hh = sh[c];
  float4 r0, r1;
  r0.x = x0.x + fmaxf(bf2f(((const ushort*)&yv)[0]) * s + hh, 0.f);
  r0.y = x0.y + fmaxf(bf2f(((const ushort*)&yv)[1]) * s + hh, 0.f);
  r0.z = x0.z + fmaxf(bf2f(((const ushort*)&yv)[2]) * s + hh, 0.f);
  r0.w = x0.w + fmaxf(bf2f(((const ushort*)&yv)[3]) * s + hh, 0.f);
  r1.x = x1.x + fmaxf(bf2f(((const ushort*)&yv)[4]) * s + hh, 0.f);
  r1.y = x1.y + fmaxf(bf2f(((const ushort*)&yv)[5]) * s + hh, 0.f);
  r1.z = x1.z + fmaxf(bf2f(((const ushort*)&yv)[6]) * s + hh, 0.f);
  r1.w = x1.w + fmaxf(bf2f(((const ushort*)&yv)[7]) * s + hh, 0.f);
  *(float4*)&out[base] = r0;
  *(float4*)&out[base + 4] = r1;
}

// ---------------------------------------------------------------------------
// Workspace (48 MB + 2 KB of >=64 MB):
//   [0,8M)    xb  bf16 [b][p][c]   (dead after attn; sc/sh alias head)
//   [8,16M)   q   bf16 [b][h][p][d]  (pre-scaled by 0.125*log2e)
//   [16,24M)  k   bf16 [b][h][p][d]
//   [24,32M)  v   bf16 [b][c][p]   (slot-permuted per 64-key tile)
//   [32,40M)  dmT bf16 [b][p][c]   (o - x, transposed)
//   [40,48M)  y   bf16 [b][c][p]
//   [48M,+2K) gs1[256], gs2[256] f32 BN accumulators (zeroed each call)
// ---------------------------------------------------------------------------
extern "C" void kernel_launch(void* const* d_in, const int* in_sizes, int n_in,
                              void* d_out, int out_size, void* d_ws, size_t ws_size,
                              hipStream_t stream) {
  const float* x = (const float*)d_in[0];
  const float* wq = (const float*)d_in[1];
  const float* wk = (const float*)d_in[2];
  const float* wv = (const float*)d_in[3];
  const float* wt = (const float*)d_in[4];
  const float* bt = (const float*)d_in[5];
  const float* gamma = (const float*)d_in[6];
  const float* beta = (const float*)d_in[7];
  float* out = (float*)d_out;
  char* wsb = (char*)d_ws;

  const size_t N = (size_t)B_ * C_ * P_;  // 4M elements
  ushort* xb = (ushort*)wsb;
  ushort* q = (ushort*)(wsb + N * 2);
  ushort* k = (ushort*)(wsb + N * 4);
  ushort* v = (ushort*)(wsb + N * 6);
  ushort* dmT = (ushort*)(wsb + N * 8);
  ushort* y = (ushort*)(wsb + N * 10);
  float* gs1 = (float*)(wsb + N * 12);
  float* gs2 = gs1 + C_;
  float* sc = (float*)wsb;   // aliases xb (dead after attn)
  float* sh = sc + C_;

  hipMemsetAsync(gs1, 0, 2 * C_ * sizeof(float), stream);
  cast_kernel<<<dim3(P_ / 64, C_ / 64, B_), 256, 0, stream>>>(x, xb);
  proj_kernel<<<dim3(P_ / 256, 12, B_), 256, 0, stream>>>(xb, wq, wk, wv, q, k, v);
  attn_kernel<<<dim3(P_ / 128, H_, B_), 512, 0, stream>>>(q, k, v, xb, dmT);
  tconv_kernel<<<dim3(P_ / 128, 4, B_), 256, 0, stream>>>(dmT, wt, bt, y, gs1, gs2);
  bnfinal_kernel<<<1, 256, 0, stream>>>(gs1, gs2, gamma, beta, sc, sh);
  final_kernel<<<(int)(N / 8 / 256), 256, 0, stream>>>(x, y, sc, sh, out);
}

// Round 15
// 121.234 us; speedup vs baseline: 1.1358x; 1.1358x over previous
//
#include <hip/hip_runtime.h>
#include <stdint.h>

#define B_ 4
#define C_ 256
#define P_ 4096
#define H_ 4
#define EPS_ 1e-5f
#define LOG2E 1.4426950408889634f

typedef __attribute__((ext_vector_type(8))) short short8v;
typedef __attribute__((ext_vector_type(4))) float floatx4;
#define MFMA16 __builtin_amdgcn_mfma_f32_16x16x32_bf16

#define GLOAD16(gp, lp)                                                     \
  __builtin_amdgcn_global_load_lds(                                         \
      (const __attribute__((address_space(1))) uint32_t*)(gp),              \
      (__attribute__((address_space(3))) uint32_t*)(lp), 16, 0, 0)

#define EXP2IP(x) asm("v_exp_f32 %0, %0" : "+v"(x))

__device__ __forceinline__ ushort f2bf(float f) {
  union { float f; uint32_t u; } c; c.f = f;
  uint32_t r = c.u + 0x7FFFu + ((c.u >> 16) & 1u);
  return (ushort)(r >> 16);
}
__device__ __forceinline__ float bf2f(ushort u) {
  union { uint32_t u; float f; } c; c.u = ((uint32_t)u) << 16; return c.f;
}

// ---------------------------------------------------------------------------
// Kernel 0: cast+transpose  x[b][c][p] f32  ->  xb[b][p][c] bf16
// ---------------------------------------------------------------------------
__global__ __launch_bounds__(256) void cast_kernel(
    const float* __restrict__ x, ushort* __restrict__ xb) {
  const int p0 = blockIdx.x * 64;
  const int c0 = blockIdx.y * 64;
  const int b = blockIdx.z;
  __shared__ float Ls[64][69];
  const int t = threadIdx.x;
#pragma unroll
  for (int r = 0; r < 4; r++) {
    int g = t + r * 256;
    int c = g >> 4, p4 = (g & 15) * 4;
    *(float4*)&Ls[c][p4] =
        *(const float4*)&x[((size_t)(b * C_ + c0 + c)) * P_ + p0 + p4];
  }
  __syncthreads();
  const int p = t >> 2, cs = (t & 3) * 16;
  size_t rowb = ((size_t)b * P_ + p0 + p) * 256 + c0 + cs;
#pragma unroll
  for (int u = 0; u < 4; u++) {
    ushort4 o;
    o.x = f2bf(Ls[cs + u * 4 + 0][p]);
    o.y = f2bf(Ls[cs + u * 4 + 1][p]);
    o.z = f2bf(Ls[cs + u * 4 + 2][p]);
    o.w = f2bf(Ls[cs + u * 4 + 3][p]);
    *(ushort4*)&xb[rowb + u * 4] = o;
  }
}

// ---------------------------------------------------------------------------
// Kernel 1: QKV projections, bf16 MFMA.
//   q/k out: [b][h][p][d] bf16 (q pre-scaled by 0.125*log2e).
//   v  out: [b][c][p] with per-64-key-tile slot permutation baked in
//   (attn's PV consumes the QK^T C-layout directly, zero P routing).
// ---------------------------------------------------------------------------
__global__ __launch_bounds__(256) void proj_kernel(
    const ushort* __restrict__ xb, const float* __restrict__ wq,
    const float* __restrict__ wk, const float* __restrict__ wv,
    ushort* __restrict__ q, ushort* __restrict__ k, ushort* __restrict__ v) {
  const int p0 = blockIdx.x * 256;
  const int which = blockIdx.y >> 2;
  const int o0 = (blockIdx.y & 3) * 64;
  const int b = blockIdx.z;
  const float* __restrict__ w = (which == 0) ? wq : (which == 1) ? wk : wv;
  const float scale = (which == 0) ? 0.125f * LOG2E : 1.0f;

  __shared__ __align__(16) uint8_t smem[33280];
  ushort* As = (ushort*)smem;  // [64 m][256 k], 8-chunk XOR swizzle
  const int t = threadIdx.x;
  const int lane = t & 63, wid = t >> 6, lr = lane & 15, lg = lane >> 4;

#pragma unroll
  for (int r = 0; r < 8; r++) {
    int g = t + r * 256;
    int m = g >> 5, ch = g & 31;
    const float* wr = &w[(size_t)(o0 + m) * 256 + ch * 8];
    float4 wa = *(const float4*)wr, wb = *(const float4*)(wr + 4);
    short8v s;
    s[0] = f2bf(wa.x * scale); s[1] = f2bf(wa.y * scale);
    s[2] = f2bf(wa.z * scale); s[3] = f2bf(wa.w * scale);
    s[4] = f2bf(wb.x * scale); s[5] = f2bf(wb.y * scale);
    s[6] = f2bf(wb.z * scale); s[7] = f2bf(wb.w * scale);
    *(short8v*)&As[m * 256 + (ch ^ (m & 7)) * 8] = s;
  }
  __syncthreads();

  const int pw0 = p0 + wid * 64;
  floatx4 acc[4][4];
#pragma unroll
  for (int mt = 0; mt < 4; mt++)
#pragma unroll
    for (int pt = 0; pt < 4; pt++) acc[mt][pt] = (floatx4){0.f, 0.f, 0.f, 0.f};

#pragma unroll
  for (int ks = 0; ks < 4; ks++) {
    const int k0 = ks * 64;
    const int cb = k0 >> 3;
    short8v bf[4][2];
#pragma unroll
    for (int pt = 0; pt < 4; pt++)
#pragma unroll
      for (int kh = 0; kh < 2; kh++)
        bf[pt][kh] = *(const short8v*)&xb[((size_t)b * P_ + pw0 + pt * 16 + lr) * 256 +
                                          k0 + kh * 32 + lg * 8];
#pragma unroll
    for (int mt = 0; mt < 4; mt++) {
      int m = mt * 16 + lr;
      short8v a0 = *(const short8v*)&As[m * 256 + ((cb + lg) ^ (m & 7)) * 8];
      short8v a1 = *(const short8v*)&As[m * 256 + ((cb + 4 + lg) ^ (m & 7)) * 8];
#pragma unroll
      for (int pt = 0; pt < 4; pt++) {
        acc[mt][pt] = MFMA16(a0, bf[pt][0], acc[mt][pt], 0, 0, 0);
        acc[mt][pt] = MFMA16(a1, bf[pt][1], acc[mt][pt], 0, 0, 0);
      }
    }
  }

  if (which < 2) {
    ushort* out = (which == 0) ? q : k;
    const int h = o0 >> 6;
#pragma unroll
    for (int pt = 0; pt < 4; pt++) {
      size_t prow = ((size_t)(b * H_ + h) * P_ + pw0 + pt * 16 + lr) * 64;
#pragma unroll
      for (int mt = 0; mt < 4; mt++) {
        ushort4 s;
        s.x = f2bf(acc[mt][pt][0]); s.y = f2bf(acc[mt][pt][1]);
        s.z = f2bf(acc[mt][pt][2]); s.w = f2bf(acc[mt][pt][3]);
        *(ushort4*)&out[prow + mt * 16 + 4 * lg] = s;
      }
    }
  } else {
    __syncthreads();
    ushort* Vt = (ushort*)smem;  // [64 c][260 p]  (slot-permuted per wid-block)
#pragma unroll
    for (int mt = 0; mt < 4; mt++)
#pragma unroll
      for (int rr = 0; rr < 4; rr++) {
        int c = mt * 16 + 4 * lg + rr;
#pragma unroll
        for (int pt = 0; pt < 4; pt++) {
          int s = 32 * (pt >> 1) + 8 * (lr >> 2) + 4 * (pt & 1) + (lr & 3);
          Vt[c * 260 + wid * 64 + s] = f2bf(acc[mt][pt][rr]);
        }
      }
    __syncthreads();
#pragma unroll
    for (int r = 0; r < 8; r++) {
      int g = t + r * 256;
      int cr = g >> 5, seg = g & 31;
      *(short8v*)&v[((size_t)(b * C_ + o0 + cr)) * P_ + p0 + seg * 8] =
          *(const short8v*)&Vt[cr * 260 + seg * 8];
    }
  }
}

// ---------------------------------------------------------------------------
// Kernel 2: flash attention.  512 threads = 8 waves. QBLK=128.
// qgrp=w&3 owns 32 queries; jgrp=w>>2 does even/odd 64-key tiles.
// Raw-exp2 softmax (no max shift; scale cancels in O/l); P packed straight
// into PV B-operand (V slot-permuted at proj); l via ones-MFMA;
// compile-time LDS addressing; gload_lds dbuf, counted vmcnt. No setprio.
// (r11-exact: verified 71.1 us / absmax 0.109, passed 3 benches.)
// grid (P/128, H, B).
// ---------------------------------------------------------------------------
__global__ __launch_bounds__(512, 4) void attn_kernel(
    const ushort* __restrict__ q, const ushort* __restrict__ k,
    const ushort* __restrict__ v, const ushort* __restrict__ xb,
    ushort* __restrict__ dmT) {
  const int i0 = blockIdx.x * 128;
  const int h = blockIdx.y;
  const int b = blockIdx.z;
  const int t = threadIdx.x;
  const int lane = t & 63, w = t >> 6, lr = lane & 15, lg = lane >> 4;
  const int qgrp = w & 3, jgrp = w >> 2;

  // jgrp block: buf0 @jgrp*32768, buf1 @+16384; each buf: K 8KB | V 8KB
  __shared__ __align__(16) uint8_t smem[65536];

  const size_t bh = (size_t)(b * H_ + h);
  const ushort* __restrict__ qg = q + bh * P_ * 64;
  const ushort* __restrict__ kb = k + bh * P_ * 64;
  const ushort* __restrict__ vb = v + ((size_t)(b * C_ + h * 64)) * P_;

  // Q fragments (B operand: col i, k = d)
  short8v bq0[2], bq1[2];
#pragma unroll
  for (int qb2 = 0; qb2 < 2; qb2++) {
    const ushort* qrow = qg + ((size_t)(i0 + qgrp * 32 + qb2 * 16 + lr)) * 64;
    bq0[qb2] = *(const short8v*)&qrow[lg * 8];
    bq1[qb2] = *(const short8v*)&qrow[32 + lg * 8];
  }

  // all-ones A fragment (bf16 1.0) for the l-row MFMA
  short8v a_ones;
#pragma unroll
  for (int e = 0; e < 8; e++) a_ones[e] = (short)0x3F80;

  // hoisted per-lane LDS read bases (element offsets; all else is constant)
  const int sw = lr & 7;
  const ushort* rb0 = (const ushort*)smem + jgrp * 16384 + lr * 64 + ((lg ^ sw) << 3);
  const ushort* rb1 = (const ushort*)smem + jgrp * 16384 + lr * 64 + (((4 + lg) ^ sw) << 3);

  // staging: running global pointers (advance by const per step)
  const int rws = lane >> 3;
  const int srow = qgrp * 16 + rws;
  const int csw = ((lane & 7) ^ rws) * 8;
  const ushort* kg = kb + (size_t)srow * 64 + csw + (size_t)jgrp * 4096;
  const ushort* vg = vb + (size_t)srow * P_ + csw + jgrp * 64;
  ushort* kd0 = (ushort*)(smem + jgrp * 32768) + qgrp * 1024;   // buf sel=0 K dest

  floatx4 o_acc[2][4], lacc[2];
#pragma unroll
  for (int qb2 = 0; qb2 < 2; qb2++) {
    lacc[qb2] = (floatx4){0.f, 0.f, 0.f, 0.f};
#pragma unroll
    for (int dt = 0; dt < 4; dt++) o_acc[qb2][dt] = (floatx4){0.f, 0.f, 0.f, 0.f};
  }

#define STAGE_(SEL)                                                         \
  do {                                                                      \
    ushort* _kd = kd0 + (SEL) * 8192;                                       \
    GLOAD16(kg, _kd);                                                       \
    GLOAD16(kg + 512, _kd + 512);                                           \
    GLOAD16(vg, _kd + 4096);                                                \
    GLOAD16(vg + 8 * (size_t)P_, _kd + 4608);                               \
    kg += 8192;                                                             \
    vg += 128;                                                              \
  } while (0)

#define COMPUTE_(SEL)                                                       \
  do {                                                                      \
    floatx4 st[2][4];                                                       \
    _Pragma("unroll") for (int jt = 0; jt < 4; jt++) {                      \
      short8v a0 = *(const short8v*)&rb0[(SEL) * 8192 + jt * 1024];         \
      short8v a1 = *(const short8v*)&rb1[(SEL) * 8192 + jt * 1024];         \
      floatx4 c0 = (floatx4){0.f, 0.f, 0.f, 0.f};                           \
      c0 = MFMA16(a0, bq0[0], c0, 0, 0, 0);                                 \
      c0 = MFMA16(a1, bq1[0], c0, 0, 0, 0);                                 \
      st[0][jt] = c0;                                                       \
      floatx4 c1 = (floatx4){0.f, 0.f, 0.f, 0.f};                           \
      c1 = MFMA16(a0, bq0[1], c1, 0, 0, 0);                                 \
      c1 = MFMA16(a1, bq1[1], c1, 0, 0, 0);                                 \
      st[1][jt] = c1;                                                       \
    }                                                                       \
    short8v bp0[2], bp1[2];                                                 \
    _Pragma("unroll") for (int qb2 = 0; qb2 < 2; qb2++) {                   \
      _Pragma("unroll") for (int jt = 0; jt < 4; jt++) {                    \
        EXP2IP(st[qb2][jt][0]); EXP2IP(st[qb2][jt][1]);                     \
        EXP2IP(st[qb2][jt][2]); EXP2IP(st[qb2][jt][3]);                     \
      }                                                                     \
      union { short8v v8; uint32_t d[4]; } u0, u1;                          \
      asm("v_cvt_pk_bf16_f32 %0, %1, %2" : "=v"(u0.d[0]) : "v"(st[qb2][0][0]), "v"(st[qb2][0][1])); \
      asm("v_cvt_pk_bf16_f32 %0, %1, %2" : "=v"(u0.d[1]) : "v"(st[qb2][0][2]), "v"(st[qb2][0][3])); \
      asm("v_cvt_pk_bf16_f32 %0, %1, %2" : "=v"(u0.d[2]) : "v"(st[qb2][1][0]), "v"(st[qb2][1][1])); \
      asm("v_cvt_pk_bf16_f32 %0, %1, %2" : "=v"(u0.d[3]) : "v"(st[qb2][1][2]), "v"(st[qb2][1][3])); \
      asm("v_cvt_pk_bf16_f32 %0, %1, %2" : "=v"(u1.d[0]) : "v"(st[qb2][2][0]), "v"(st[qb2][2][1])); \
      asm("v_cvt_pk_bf16_f32 %0, %1, %2" : "=v"(u1.d[1]) : "v"(st[qb2][2][2]), "v"(st[qb2][2][3])); \
      asm("v_cvt_pk_bf16_f32 %0, %1, %2" : "=v"(u1.d[2]) : "v"(st[qb2][3][0]), "v"(st[qb2][3][1])); \
      asm("v_cvt_pk_bf16_f32 %0, %1, %2" : "=v"(u1.d[3]) : "v"(st[qb2][3][2]), "v"(st[qb2][3][3])); \
      bp0[qb2] = u0.v8;                                                     \
      bp1[qb2] = u1.v8;                                                     \
    }                                                                       \
    _Pragma("unroll") for (int dt = 0; dt < 4; dt++) {                      \
      short8v a0 = *(const short8v*)&rb0[(SEL) * 8192 + 4096 + dt * 1024];  \
      short8v a1 = *(const short8v*)&rb1[(SEL) * 8192 + 4096 + dt * 1024];  \
      o_acc[0][dt] = MFMA16(a0, bp0[0], o_acc[0][dt], 0, 0, 0);             \
      o_acc[0][dt] = MFMA16(a1, bp1[0], o_acc[0][dt], 0, 0, 0);             \
      o_acc[1][dt] = MFMA16(a0, bp0[1], o_acc[1][dt], 0, 0, 0);             \
      o_acc[1][dt] = MFMA16(a1, bp1[1], o_acc[1][dt], 0, 0, 0);             \
    }                                                                       \
    lacc[0] = MFMA16(a_ones, bp0[0], lacc[0], 0, 0, 0);                     \
    lacc[0] = MFMA16(a_ones, bp1[0], lacc[0], 0, 0, 0);                     \
    lacc[1] = MFMA16(a_ones, bp0[1], lacc[1], 0, 0, 0);                     \
    lacc[1] = MFMA16(a_ones, bp1[1], lacc[1], 0, 0, 0);                     \
  } while (0)

  // ---- pipeline: 32 tiles/group (even/odd interleave via jgrp) ----
  STAGE_(0);
  for (int it = 0; it < 15; ++it) {
    STAGE_(1);
    asm volatile("s_waitcnt vmcnt(8)" ::: "memory");
    __builtin_amdgcn_s_barrier();
    COMPUTE_(0);
    asm volatile("" ::: "memory");
    __builtin_amdgcn_s_barrier();
    STAGE_(0);
    asm volatile("s_waitcnt vmcnt(8)" ::: "memory");
    __builtin_amdgcn_s_barrier();
    COMPUTE_(1);
    asm volatile("" ::: "memory");
    __builtin_amdgcn_s_barrier();
  }
  STAGE_(1);
  asm volatile("s_waitcnt vmcnt(8)" ::: "memory");
  __builtin_amdgcn_s_barrier();
  COMPUTE_(0);
  asm volatile("s_waitcnt vmcnt(0)" ::: "memory");
  __builtin_amdgcn_s_barrier();
  COMPUTE_(1);
  __syncthreads();
#undef STAGE_
#undef COMPUTE_

  // ---- epilogue: combine groups, normalize, write dmT = bf16(o - x) ----
  float* Opart = (float*)smem;                  // [4 qgrp][2 qb][4 dt][256]
  float* lpart = (float*)(smem + 32768);        // [128]
  if (jgrp == 1) {
#pragma unroll
    for (int qb2 = 0; qb2 < 2; qb2++) {
#pragma unroll
      for (int dt = 0; dt < 4; dt++)
        *(floatx4*)&Opart[(((qgrp * 2 + qb2) * 4 + dt) << 8) + (lane << 2)] =
            o_acc[qb2][dt];
      if (lg == 0) lpart[qgrp * 32 + qb2 * 16 + lr] = lacc[qb2][0];
    }
  }
  __syncthreads();
  ushort* Os = (ushort*)(smem + 36864);         // [128 i][72 d]
  if (jgrp == 0) {
#pragma unroll
    for (int qb2 = 0; qb2 < 2; qb2++) {
      const int i = qgrp * 32 + qb2 * 16 + lr;
      const float invl = 1.f / (lacc[qb2][0] + lpart[i]);
#pragma unroll
      for (int dt = 0; dt < 4; dt++) {
        floatx4 o2 = o_acc[qb2][dt] +
                     *(const floatx4*)&Opart[(((qgrp * 2 + qb2) * 4 + dt) << 8) + (lane << 2)];
        uint2 pk2;
        asm("v_cvt_pk_bf16_f32 %0, %1, %2" : "=v"(pk2.x)
            : "v"(o2[0] * invl), "v"(o2[1] * invl));
        asm("v_cvt_pk_bf16_f32 %0, %1, %2" : "=v"(pk2.y)
            : "v"(o2[2] * invl), "v"(o2[3] * invl));
        *(uint2*)&Os[i * 72 + dt * 16 + 4 * lg] = pk2;
      }
    }
  }
  __syncthreads();
  const int ei = t >> 2, edq = t & 3;
  size_t rowb = ((size_t)b * P_ + i0 + ei) * 256 + h * 64 + edq * 16;
#pragma unroll
  for (int u = 0; u < 2; u++) {
    short8v xv8 = *(const short8v*)&xb[rowb + u * 8];
    short8v ov8 = *(const short8v*)&Os[ei * 72 + edq * 16 + u * 8];
    short8v res;
#pragma unroll
    for (int e = 0; e < 8; e++) {
      float d = bf2f(((const ushort*)&ov8)[e]) - bf2f(((const ushort*)&xv8)[e]);
      ((ushort*)&res)[e] = f2bf(d);
    }
    *(short8v*)&dmT[rowb + u * 8] = res;
  }
}

// ---------------------------------------------------------------------------
// Kernel 3: y = wt @ dm + bt, bf16 MFMA.  y bf16 [b][c][p].
// ---------------------------------------------------------------------------
__global__ __launch_bounds__(256) void tconv_kernel(
    const ushort* __restrict__ dmT, const float* __restrict__ wt,
    const float* __restrict__ bt, ushort* __restrict__ y) {
  const int p0 = blockIdx.x * 128;
  const int o0 = blockIdx.y * 64;
  const int b = blockIdx.z;
  __shared__ __align__(16) uint8_t smem[32768];
  ushort* As = (ushort*)smem;  // [64 m][256 k] swizzled
  const int t = threadIdx.x;
  const int lane = t & 63, wid = t >> 6, lr = lane & 15, lg = lane >> 4;

#pragma unroll
  for (int r = 0; r < 8; r++) {
    int g = t + r * 256;
    int m = g >> 5, ch = g & 31;
    const float* wr = &wt[(size_t)(o0 + m) * 256 + ch * 8];
    float4 wa = *(const float4*)wr, wb = *(const float4*)(wr + 4);
    short8v s;
    s[0] = f2bf(wa.x); s[1] = f2bf(wa.y); s[2] = f2bf(wa.z); s[3] = f2bf(wa.w);
    s[4] = f2bf(wb.x); s[5] = f2bf(wb.y); s[6] = f2bf(wb.z); s[7] = f2bf(wb.w);
    *(short8v*)&As[m * 256 + (ch ^ (m & 7)) * 8] = s;
  }
  __syncthreads();

  const int pw0 = p0 + wid * 32;
  floatx4 acc[4][2];
#pragma unroll
  for (int mt = 0; mt < 4; mt++)
#pragma unroll
    for (int pt = 0; pt < 2; pt++) acc[mt][pt] = (floatx4){0.f, 0.f, 0.f, 0.f};

#pragma unroll
  for (int ks = 0; ks < 4; ks++) {
    const int k0 = ks * 64;
    const int cb = k0 >> 3;
    short8v bf[2][2];
#pragma unroll
    for (int pt = 0; pt < 2; pt++)
#pragma unroll
      for (int kh = 0; kh < 2; kh++)
        bf[pt][kh] = *(const short8v*)&dmT[((size_t)b * P_ + pw0 + pt * 16 + lr) * 256 +
                                           k0 + kh * 32 + lg * 8];
#pragma unroll
    for (int mt = 0; mt < 4; mt++) {
      int m = mt * 16 + lr;
      short8v a0 = *(const short8v*)&As[m * 256 + ((cb + lg) ^ (m & 7)) * 8];
      short8v a1 = *(const short8v*)&As[m * 256 + ((cb + 4 + lg) ^ (m & 7)) * 8];
#pragma unroll
      for (int pt = 0; pt < 2; pt++) {
        acc[mt][pt] = MFMA16(a0, bf[pt][0], acc[mt][pt], 0, 0, 0);
        acc[mt][pt] = MFMA16(a1, bf[pt][1], acc[mt][pt], 0, 0, 0);
      }
    }
  }

  __syncthreads();
  ushort* Yt = (ushort*)smem;  // [64 c][132 p]
#pragma unroll
  for (int mt = 0; mt < 4; mt++) {
    float4 bv = *(const float4*)&bt[o0 + mt * 16 + 4 * lg];
#pragma unroll
    for (int rr = 0; rr < 4; rr++) {
      float bias = (rr == 0) ? bv.x : (rr == 1) ? bv.y : (rr == 2) ? bv.z : bv.w;
      int c = mt * 16 + 4 * lg + rr;
#pragma unroll
      for (int pt = 0; pt < 2; pt++)
        Yt[c * 132 + wid * 32 + pt * 16 + lr] = f2bf(acc[mt][pt][rr] + bias);
    }
  }
  __syncthreads();
#pragma unroll
  for (int r = 0; r < 4; r++) {
    int g = t + r * 256;
    int cr = g >> 4, seg = g & 15;
    *(short8v*)&y[((size_t)(b * C_ + o0 + cr)) * P_ + p0 + seg * 8] =
        *(const short8v*)&Yt[cr * 132 + seg * 8];
  }
}

// ---------------------------------------------------------------------------
// Kernel 4: per-channel BN stats over (B,P); y is bf16.
// ---------------------------------------------------------------------------
__global__ __launch_bounds__(256) void bnstats_kernel(
    const ushort* __restrict__ y, const float* __restrict__ gamma,
    const float* __restrict__ beta, float* __restrict__ sc,
    float* __restrict__ sh) {
  const int c = blockIdx.x;
  const int t = threadIdx.x;
  float s1 = 0.f, s2 = 0.f;
#pragma unroll
  for (int r = 0; r < 8; r++) {
    int e = t + r * 256;
    int b = e >> 9;
    int p8 = (e & 511) * 8;
    short8v yv = *(const short8v*)&y[((size_t)(b * C_ + c)) * P_ + p8];
#pragma unroll
    for (int j = 0; j < 8; j++) {
      float f = bf2f(((const ushort*)&yv)[j]);
      s1 += f; s2 += f * f;
    }
  }
#pragma unroll
  for (int off = 32; off > 0; off >>= 1) {
    s1 += __shfl_xor(s1, off);
    s2 += __shfl_xor(s2, off);
  }
  __shared__ float r1[4], r2[4];
  const int w = t >> 6;
  if ((t & 63) == 0) { r1[w] = s1; r2[w] = s2; }
  __syncthreads();
  if (t == 0) {
    float a1 = r1[0] + r1[1] + r1[2] + r1[3];
    float a2 = r2[0] + r2[1] + r2[2] + r2[3];
    const float n = (float)(B_ * P_);
    float mean = a1 / n;
    float var = a2 / n - mean * mean;
    float rstd = rsqrtf(var + EPS_);
    float g = gamma[c] * rstd;
    sc[c] = g;
    sh[c] = beta[c] - mean * g;
  }
}

// ---------------------------------------------------------------------------
// Kernel 5: out = x + relu(y*scale + shift); y bf16, out f32.
// ---------------------------------------------------------------------------
__global__ __launch_bounds__(256) void final_kernel(
    const float* __restrict__ x, const ushort* __restrict__ y,
    const float* __restrict__ sc, const float* __restrict__ sh,
    float* __restrict__ out) {
  const int f = blockIdx.x * 256 + threadIdx.x;
  const size_t base = (size_t)f * 8;
  const int c = (int)((base >> 12) & (C_ - 1));
  short8v yv = *(const short8v*)&y[base];
  float4 x0 = *(const float4*)&x[base];
  float4 x1 = *(const float4*)&x[base + 4];
  const float s = sc[c], hh = sh[c];
  float4 r0, r1;
  r0.x = x0.x + fmaxf(bf2f(((const ushort*)&yv)[0]) * s + hh, 0.f);
  r0.y = x0.y + fmaxf(bf2f(((const ushort*)&yv)[1]) * s + hh, 0.f);
  r0.z = x0.z + fmaxf(bf2f(((const ushort*)&yv)[2]) * s + hh, 0.f);
  r0.w = x0.w + fmaxf(bf2f(((const ushort*)&yv)[3]) * s + hh, 0.f);
  r1.x = x1.x + fmaxf(bf2f(((const ushort*)&yv)[4]) * s + hh, 0.f);
  r1.y = x1.y + fmaxf(bf2f(((const ushort*)&yv)[5]) * s + hh, 0.f);
  r1.z = x1.z + fmaxf(bf2f(((const ushort*)&yv)[6]) * s + hh, 0.f);
  r1.w = x1.w + fmaxf(bf2f(((const ushort*)&yv)[7]) * s + hh, 0.f);
  *(float4*)&out[base] = r0;
  *(float4*)&out[base + 4] = r1;
}

// ---------------------------------------------------------------------------
// Workspace (48 MB of >=64 MB):
//   [0,8M)   xb  bf16 [b][p][c]   (dead after attn; sc/sh alias head)
//   [8,16M)  q   bf16 [b][h][p][d]  (pre-scaled by 0.125*log2e)
//   [16,24M) k   bf16 [b][h][p][d]
//   [24,32M) v   bf16 [b][c][p]   (slot-permuted per 64-key tile)
//   [32,40M) dmT bf16 [b][p][c]   (o - x, transposed)
//   [40,48M) y   bf16 [b][c][p]
// ---------------------------------------------------------------------------
extern "C" void kernel_launch(void* const* d_in, const int* in_sizes, int n_in,
                              void* d_out, int out_size, void* d_ws, size_t ws_size,
                              hipStream_t stream) {
  const float* x = (const float*)d_in[0];
  const float* wq = (const float*)d_in[1];
  const float* wk = (const float*)d_in[2];
  const float* wv = (const float*)d_in[3];
  const float* wt = (const float*)d_in[4];
  const float* bt = (const float*)d_in[5];
  const float* gamma = (const float*)d_in[6];
  const float* beta = (const float*)d_in[7];
  float* out = (float*)d_out;
  char* wsb = (char*)d_ws;

  const size_t N = (size_t)B_ * C_ * P_;  // 4M elements
  ushort* xb = (ushort*)wsb;
  ushort* q = (ushort*)(wsb + N * 2);
  ushort* k = (ushort*)(wsb + N * 4);
  ushort* v = (ushort*)(wsb + N * 6);
  ushort* dmT = (ushort*)(wsb + N * 8);
  ushort* y = (ushort*)(wsb + N * 10);
  float* sc = (float*)wsb;   // aliases xb (dead after attn)
  float* sh = sc + C_;

  cast_kernel<<<dim3(P_ / 64, C_ / 64, B_), 256, 0, stream>>>(x, xb);
  proj_kernel<<<dim3(P_ / 256, 12, B_), 256, 0, stream>>>(xb, wq, wk, wv, q, k, v);
  attn_kernel<<<dim3(P_ / 128, H_, B_), 512, 0, stream>>>(q, k, v, xb, dmT);
  tconv_kernel<<<dim3(P_ / 128, 4, B_), 256, 0, stream>>>(dmT, wt, bt, y);
  bnstats_kernel<<<C_, 256, 0, stream>>>(y, gamma, beta, sc, sh);
  final_kernel<<<(int)(N / 8 / 256), 256, 0, stream>>>(x, y, sc, sh, out);
}